// Round 13
// baseline (410.130 us; speedup 1.0000x reference)
//
#include <hip/hip_runtime.h>
#include <hip/hip_bf16.h>
#include <math.h>

// ---------------------------------------------------------------------------
// ModelFC_49134425866355 on MI355X (gfx950)
//
// out0[row] = dot(LN(gelu(E@W1+b1))*g+b, W2[:,sel]) + b2[sel]
//           = rstd*(D - mu*Gw) + Bw     (algebraic LN+GEMV fusion)
// gemm1p (r11 config, best timed): A staged as FP32 via async global_load_lds
// (no cvt_e pass), fp32->bf16 at fragment-read time; granule XOR swizzle
// pos = g ^ (row&15) (2-way LDS aliasing is free on gfx950).
// finalize is MERGED into own_lnlog via the last-block pattern (device-scope
// atomicAdd + threadfence release/acquire) -> one fewer kernel boundary.
// 4 kernels: prep_duo | own_lnlog_fin | gemm1p | out_scores.
// ---------------------------------------------------------------------------

typedef __bf16 bf16_t;
typedef __bf16  bf16x8  __attribute__((ext_vector_type(8)));
typedef float   floatx4 __attribute__((ext_vector_type(4)));

__device__ __forceinline__ float gelu_exact(float x) {
    return 0.5f * x * (1.0f + erff(x * 0.7071067811865475f));
}
// tanh-form gelu via sigmoid; |err|<~1e-3, below bf16 rounding of bulk path.
__device__ __forceinline__ float gelu_fast(float x) {
    const float z = x * (1.0f + 0.044715f * x * x);
    return __fdividef(x, 1.0f + __expf(-1.5957691216f * z));
}

// async global->LDS, 16B per lane; lds base wave-uniform (HW adds lane*16).
// OFFSET ARG STAYS 0 — nonzero immediate is unverified and broke round 5.
__device__ __forceinline__ void gl_lds16(const void* g, void* l) {
    __builtin_amdgcn_global_load_lds(
        (const __attribute__((address_space(1))) void*)g,
        (__attribute__((address_space(3))) void*)l, 16, 0, 0);
}

// ---------------------------------------------------------------------------
// prep_duo: [0,288) tr_w1 (LDS-tiled transpose) | [288,1056) own_h
// Also zeroes the completion counter for own_lnlog_fin (stream-ordered).
// ---------------------------------------------------------------------------
__global__ __launch_bounds__(256) void prep_duo(
        const float* __restrict__ E, const float* __restrict__ W1,
        bf16_t* __restrict__ W1t, float* __restrict__ hpart,
        int* __restrict__ cnt) {
    __shared__ alignas(16) char smemc[16640];   // max(sT 64x65 fp32, sE 6KB)
    const int bid = blockIdx.x;
    const int tid = threadIdx.x;
    if (bid == 0 && tid == 0) *cnt = 0;         // reset last-block counter

    if (bid < 288) {                    // ---- tr_w1: 64x64 LDS-tiled transpose
        float* sT = (float*)smemc;      // [64][65]
        const int bk = bid % 12, bn = bid / 12;
        const int k0 = bk * 64, n0 = bn * 64;
        #pragma unroll
        for (int i = 0; i < 16; ++i) {
            const int idx = tid + i * 256;
            const int kk = idx >> 6, nn = idx & 63;
            sT[kk * 65 + nn] = W1[(size_t)(k0 + kk) * 1536 + n0 + nn];
        }
        __syncthreads();
        #pragma unroll
        for (int i = 0; i < 16; ++i) {
            const int idx = tid + i * 256;
            const int nn = idx >> 6, kk = idx & 63;
            W1t[(size_t)(n0 + nn) * 768 + k0 + kk] = (bf16_t)sT[kk * 65 + nn];
        }
    } else {                            // ---- own_h: hpart[kq][512][1536]
        float* sE = (float*)smemc;      // [8][192]
        const int b  = bid - 288;       // 0..767
        const int a  = b & 63;
        const int rest = b >> 6;        // 0..11
        const int by = rest % 3, kq = rest / 3;

        const float* Ebase = E + (size_t)(520 * a) * 768 + kq * 192;
        for (int idx = tid; idx < 1536; idx += 256) {
            const int row = idx / 192, i = idx - row * 192;
            sE[idx] = Ebase[(size_t)row * 768 + i];
        }
        __syncthreads();

        const int c0 = by * 512 + tid * 2;
        const float* w1p = W1 + (size_t)(kq * 192) * 1536 + c0;
        float ax[8] = {}, ay[8] = {};
        for (int k = 0; k < 192; ++k) {
            const float2 w = *(const float2*)(w1p + (size_t)k * 1536);
            #pragma unroll
            for (int j = 0; j < 8; ++j) {
                const float e = sE[j * 192 + k];   // LDS broadcast
                ax[j] += w.x * e;
                ay[j] += w.y * e;
            }
        }
        #pragma unroll
        for (int j = 0; j < 8; ++j)
            *(float2*)(hpart + (size_t)(kq * 512 + a * 8 + j) * 1536 + c0)
                = make_float2(ax[j], ay[j]);
    }
}

// ---------------------------------------------------------------------------
// own_lnlog_fin: per row (512 blocks): h = gelu_exact(sum of 4 k-partials +
// b1), fp32 LN in LDS, own[row][100] = LNrow @ W2 + b2 (in-block k-split x2).
// The LAST block to finish (device-scope atomic counter) runs the finalize
// body: VG_scores / VG_index (fp32-exact, first-max) + u/Gw/Bw constants.
// ---------------------------------------------------------------------------
__global__ __launch_bounds__(256) void own_lnlog_fin(
        const float* __restrict__ hpart, const float* __restrict__ b1,
        const float* __restrict__ lng,  const float* __restrict__ lnb,
        const float* __restrict__ W2,   const float* __restrict__ b2,
        float* __restrict__ own, float* __restrict__ out,
        float* __restrict__ u, float* __restrict__ gwbw,
        int* __restrict__ cnt) {
    __shared__ float srow[1536];
    __shared__ float red8[8];
    __shared__ float redl[128];
    __shared__ int   slast, ssel;
    __shared__ float rg[4], rb[4];
    const int row = blockIdx.x, tid = threadIdx.x;
    const int lane = tid & 63, wv = tid >> 6;

    float x[6];
    #pragma unroll
    for (int i = 0; i < 6; ++i) {
        const int c = tid + i * 256;
        x[i] = gelu_exact(hpart[(size_t)row * 1536 + c]
                        + hpart[(size_t)(512 + row) * 1536 + c]
                        + hpart[(size_t)(1024 + row) * 1536 + c]
                        + hpart[(size_t)(1536 + row) * 1536 + c] + b1[c]);
    }
    float s = 0.f;
    #pragma unroll
    for (int i = 0; i < 6; ++i) s += x[i];
    #pragma unroll
    for (int o = 32; o > 0; o >>= 1) s += __shfl_xor(s, o, 64);
    if (lane == 0) red8[wv] = s;
    __syncthreads();
    const float mu = (red8[0] + red8[1] + red8[2] + red8[3]) * (1.0f / 1536.0f);

    float s2 = 0.f;
    #pragma unroll
    for (int i = 0; i < 6; ++i) { float d = x[i] - mu; s2 += d * d; }
    #pragma unroll
    for (int o = 32; o > 0; o >>= 1) s2 += __shfl_xor(s2, o, 64);
    if (lane == 0) red8[4 + wv] = s2;
    __syncthreads();
    const float rstd = rsqrtf((red8[4] + red8[5] + red8[6] + red8[7]) * (1.0f / 1536.0f) + 1e-12f);

    #pragma unroll
    for (int i = 0; i < 6; ++i) {
        const int c = tid + i * 256;
        srow[c] = (x[i] - mu) * rstd * lng[c] + lnb[c];
    }
    __syncthreads();

    // logits for this row: (d, ks) = (128, 2)
    const int d  = tid & 127;
    const int ks = tid >> 7;
    const int dd = d < 100 ? d : 99;
    float acc = ks ? 0.0f : b2[dd];
    const float* hr = srow + ks * 768;
    for (int k = 0; k < 768; ++k)
        acc += hr[k] * W2[(size_t)(ks * 768 + k) * 100 + dd];
    if (ks) redl[d] = acc;
    __syncthreads();
    if (!ks && d < 100) own[(size_t)row * 100 + d] = acc + redl[d];

    // ---- last-block finalize (canonical threadfence-reduction pattern)
    __syncthreads();                       // all own-writes of this block issued
    if (tid == 0) {
        __threadfence();                   // release this block's own[] row
        const int old = atomicAdd(cnt, 1); // device-scope [m20]
        slast = (old == 511);
    }
    __syncthreads();
    if (!slast) return;
    __threadfence();                       // acquire all blocks' own[] rows

    #pragma unroll
    for (int h = 0; h < 2; ++h) {
        const int e = tid + h * 256;       // rows tid and tid+256
        volatile const float* r = own + (size_t)e * 100;
        float best = r[0]; int bi = 0;
        for (int i = 1; i < 100; ++i) {
            const float v = r[i];
            if (v > best) { best = v; bi = i; }   // strict > keeps first max
        }
        float ssum = 0.f;
        for (int i = 0; i < 100; ++i) ssum += expf(r[i] - best);
        out[262144 + e] = 1.0f / ssum;     // VG_scores
        out[262656 + e] = (float)bi;       // VG_scores_index
        if (e == 511) ssel = bi;
    }
    __syncthreads();
    const int sel = ssel;

    float gw = 0.f, bw = 0.f;
    #pragma unroll
    for (int i = 0; i < 6; ++i) {
        const int c = tid + i * 256;
        const float wv2 = W2[(size_t)c * 100 + sel];
        const float uu = lng[c] * wv2;
        u[c] = uu;
        gw += uu;
        bw += lnb[c] * wv2;
    }
    #pragma unroll
    for (int o = 32; o > 0; o >>= 1) {
        gw += __shfl_xor(gw, o, 64);
        bw += __shfl_xor(bw, o, 64);
    }
    if (lane == 0) { rg[wv] = gw; rb[wv] = bw; }
    __syncthreads();
    if (tid == 0) {
        gwbw[0] = rg[0] + rg[1] + rg[2] + rg[3];
        gwbw[1] = rb[0] + rb[1] + rb[2] + rb[3] + b2[sel];
    }
}

// ---------------------------------------------------------------------------
// gemm1p (r11 config, verbatim): [32768,768]x[768,1536], 128x128 tile, BK=64.
// A staged as FP32 via global_load_lds into a granule-swizzled LDS tile
// (pos = g ^ (row&15), 16B granules, 16/row); fragments read as 2x b128 +
// RNE cast to bf16 (bit-identical numerics to the old cvt_e path).
// B staged via global_load_lds (bf16, source-swizzled, unchanged).
// Epilogue: LDS round-trip stats (S1,S2,D). No act matrix.
// ---------------------------------------------------------------------------
__global__ __launch_bounds__(256) void gemm1p(
        const float* __restrict__ E, const bf16_t* __restrict__ Bt,
        const float* __restrict__ bias, const float* __restrict__ u,
        float* __restrict__ pS1, float* __restrict__ pS2,
        float* __restrict__ pD) {
    constexpr int K = 768;
    __shared__ alignas(16) char smem[49152];   // sAf 32KB | sB 16KB; epi reuse
    float*  sAf = (float*)smem;                // [128][64] fp32, swizzled
    bf16_t* sB  = (bf16_t*)(smem + 32768);     // [128][64] bf16, swizzled

    // XCD-aware remap: 12 n-tiles of one m-tile land on one XCD
    const int linear = blockIdx.x + gridDim.x * blockIdx.y;
    const int xcd  = linear & 7;
    const int slot = linear >> 3;
    const int bx = slot % gridDim.x;
    const int by = (slot / gridDim.x) * 8 + xcd;

    const int tid  = threadIdx.x;
    const int lane = tid & 63;
    const int wave = tid >> 6;
    const int wr = wave >> 1, wc = wave & 1;
    const int m0 = by * 128;
    const int n0 = bx * 128;
    const int q  = lane >> 4;
    const int l15 = lane & 15;

    // ---- A staging bases: slot s = c*256+tid; r = s>>4 (16 granules/row),
    //      pos = s&15, logical granule g = pos ^ (r&15); source = row r, g*4.
    const float* gAf[8]; float* lAf[8];
    #pragma unroll
    for (int c = 0; c < 8; ++c) {
        const int s   = c * 256 + tid;
        const int r   = s >> 4;
        const int pos = s & 15;
        const int g   = pos ^ (r & 15);
        gAf[c] = E + (size_t)(m0 + r) * K + g * 4;
        lAf[c] = sAf + (c * 256 + wave * 64) * 4;   // wave-uniform base
    }
    // ---- B staging bases (bf16, 8 granules of 16B per row, col^row&7)
    const bf16_t* gB[4]; bf16_t* lB[4];
    #pragma unroll
    for (int c = 0; c < 4; ++c) {
        const int s    = c * 256 + tid;
        const int row  = s >> 3;
        const int col  = s & 7;
        const int gcol = col ^ (row & 7);
        gB[c] = Bt + (size_t)(n0 + row) * K + gcol * 8;
        lB[c] = sB + (c * 256 + wave * 64) * 8;
    }
    // ---- read bases (K-step invariant)
    const float* rAf[4]; const bf16_t* rB[4];
    #pragma unroll
    for (int t4 = 0; t4 < 4; ++t4) {
        rAf[t4] = sAf + (wr * 64 + t4 * 16 + l15) * 64;  // row&15 == l15
        rB[t4]  = sB + (wc * 64 + t4 * 16 + l15) * 64;
    }
    const int q2 = q * 2;
    // A fragment: logical chunk j = ks*4+q -> granules 2j, 2j+1 at swizzled
    // positions (2j+h)^l15; float offsets = pos*4.
    const int oA00 = ((q2)     ^ l15) * 4, oA01 = ((q2 + 1) ^ l15) * 4;
    const int oA10 = ((q2 + 8) ^ l15) * 4, oA11 = ((q2 + 9) ^ l15) * 4;
    const int c0 = ((q)     ^ (lane & 7)) * 8;   // B: rB row & 7 == lane & 7
    const int c1 = ((4 + q) ^ (lane & 7)) * 8;

    floatx4 acc[4][4] = {};

    #pragma unroll
    for (int kt = 0; kt < 12; ++kt) {
        const int k0 = kt * 64;
        __syncthreads();   // prev compute done before LDS overwrite
        #pragma unroll
        for (int c = 0; c < 4; ++c) gl_lds16(gB[c] + k0, lB[c]);
        #pragma unroll
        for (int c = 0; c < 8; ++c) gl_lds16(gAf[c] + k0, lAf[c]);
        __syncthreads();   // drain DMA, then barrier

        #pragma unroll
        for (int ks = 0; ks < 2; ++ks) {
            const int co  = ks ? c1 : c0;
            const int oa0 = ks ? oA10 : oA00;
            const int oa1 = ks ? oA11 : oA01;
            bf16x8 af[4], bfr[4];
            #pragma unroll
            for (int t4 = 0; t4 < 4; ++t4) {
                const float4 v0 = *(const float4*)(rAf[t4] + oa0);
                const float4 v1 = *(const float4*)(rAf[t4] + oa1);
                af[t4][0] = (bf16_t)v0.x; af[t4][1] = (bf16_t)v0.y;
                af[t4][2] = (bf16_t)v0.z; af[t4][3] = (bf16_t)v0.w;
                af[t4][4] = (bf16_t)v1.x; af[t4][5] = (bf16_t)v1.y;
                af[t4][6] = (bf16_t)v1.z; af[t4][7] = (bf16_t)v1.w;
                bfr[t4] = *(const bf16x8*)(rB[t4] + co);
            }
            #pragma unroll
            for (int mt = 0; mt < 4; ++mt)
                #pragma unroll
                for (int nt = 0; nt < 4; ++nt)
                    acc[mt][nt] = __builtin_amdgcn_mfma_f32_16x16x32_bf16(
                        af[mt], bfr[nt], acc[mt][nt], 0, 0, 0);
        }
    }

    // ---- stats epilogue via LDS (low VGPR). C/D layout: col=l15, row=q*4+r.
    __syncthreads();                       // all tile ds_reads done
    bf16_t* sh = (bf16_t*)smem;            // [128][130] bf16 = 33280 B
    float*  su = (float*)(smem + 33280);   // u[n0..n0+127]          512 B
    float*  sp = (float*)(smem + 33792);   // [256][3] partials     3072 B

    if (tid < 128) su[tid] = u[n0 + tid];
    float bias4[4];
    #pragma unroll
    for (int nt = 0; nt < 4; ++nt) bias4[nt] = bias[n0 + wc * 64 + nt * 16 + l15];

    #pragma unroll
    for (int mt = 0; mt < 4; ++mt)
        #pragma unroll
        for (int nt = 0; nt < 4; ++nt)
            #pragma unroll
            for (int r = 0; r < 4; ++r) {
                const int rowl = wr * 64 + mt * 16 + q * 4 + r;
                const int coll = wc * 64 + nt * 16 + l15;
                sh[rowl * 130 + coll] = (bf16_t)gelu_fast(acc[mt][nt][r] + bias4[nt]);
            }
    __syncthreads();

    // phase 2: thread = (row, half); reduce 64 cols each
    {
        const int rowl = tid >> 1, half = tid & 1;
        const bf16_t* hp = sh + rowl * 130 + half * 64;
        const float*  up = su + half * 64;
        float s1 = 0.f, s2 = 0.f, dd = 0.f;
        #pragma unroll
        for (int c = 0; c < 64; ++c) {
            const float v = (float)hp[c];
            s1 += v; s2 += v * v; dd += v * up[c];
        }
        sp[tid * 3 + 0] = s1; sp[tid * 3 + 1] = s2; sp[tid * 3 + 2] = dd;
    }
    __syncthreads();
    if (tid < 128) {
        const float* p0 = sp + (2 * tid) * 3;
        const float* p1 = sp + (2 * tid + 1) * 3;
        const size_t idx = (size_t)bx * 32768 + (m0 + tid);
        pS1[idx] = p0[0] + p1[0];
        pS2[idx] = p0[1] + p1[1];
        pD[idx]  = p0[2] + p1[2];
    }
}

// ---------------------------------------------------------------------------
// out_scores: out[t*8+k] = rstd*(D - mu*Gw) + Bw   (32768 threads)
// ---------------------------------------------------------------------------
__global__ __launch_bounds__(256) void out_scores(
        const float* __restrict__ pS1, const float* __restrict__ pS2,
        const float* __restrict__ pD,  const float* __restrict__ gwbw,
        float* __restrict__ out) {
    const int t = blockIdx.x * 256 + threadIdx.x;   // 32768 exactly
    float s1 = 0.f, s2 = 0.f, d = 0.f;
    #pragma unroll
    for (int nt = 0; nt < 12; ++nt) {
        const size_t idx = (size_t)nt * 32768 + t;
        s1 += pS1[idx]; s2 += pS2[idx]; d += pD[idx];
    }
    const float mu   = s1 * (1.0f / 1536.0f);
    const float var  = s2 * (1.0f / 1536.0f) - mu * mu;
    const float rstd = rsqrtf(var + 1e-12f);
    const float v = rstd * (d - mu * gwbw[0]) + gwbw[1];
    const float4 f = make_float4(v, v, v, v);
    float4* o = (float4*)(out + (size_t)t * 8);
    o[0] = f; o[1] = f;
}

// ---------------------------------------------------------------------------
extern "C" void kernel_launch(void* const* d_in, const int* in_sizes, int n_in,
                              void* d_out, int out_size, void* d_ws, size_t ws_size,
                              hipStream_t stream) {
    const float* E   = (const float*)d_in[0];
    const float* W1  = (const float*)d_in[1];
    const float* b1  = (const float*)d_in[2];
    const float* lng = (const float*)d_in[3];
    const float* lnb = (const float*)d_in[4];
    const float* W2  = (const float*)d_in[5];
    const float* b2  = (const float*)d_in[6];
    float* out = (float*)d_out;

    char* w = (char*)d_ws;
    auto carve = [&](size_t bytes) {
        void* p = (void*)w;
        w += (bytes + 255) & ~(size_t)255;
        return p;
    };
    bf16_t* W1t   = (bf16_t*)carve((size_t)1536 * 768 * 2);    //  2.4 MB
    float*  hpart = (float*)carve((size_t)4 * 512 * 1536 * 4); // 12.6 MB
    float*  own   = (float*)carve((size_t)512 * 100 * 4);
    float*  u     = (float*)carve(1536 * 4);
    float*  gwbw  = (float*)carve(256);
    int*    cnt   = (int*)carve(256);
    float*  pS1   = (float*)carve((size_t)12 * 32768 * 4);     //  1.6 MB
    float*  pS2   = (float*)carve((size_t)12 * 32768 * 4);
    float*  pD    = (float*)carve((size_t)12 * 32768 * 4);

    // 1) prep: W1 transpose (tiled) + own-row k-partials + counter reset
    prep_duo<<<1056, 256, 0, stream>>>(E, W1, W1t, hpart, cnt);
    // 2) own rows: LN + logits; last block finalizes (VG outs, u/Gw/Bw)
    own_lnlog_fin<<<512, 256, 0, stream>>>(hpart, b1, lng, lnb, W2, b2,
                                           own, out, u, gwbw, cnt);
    // 3) fused GEMM (A = fp32 E via async DMA, cvt at fragment read)
    gemm1p<<<dim3(12, 256), 256, 0, stream>>>(E, W1t, b1, u, pS1, pS2, pD);
    // 4) combine partials -> output 0
    out_scores<<<128, 256, 0, stream>>>(pS1, pS2, pD, gwbw, out);
}

// Round 14
// 346.309 us; speedup vs baseline: 1.1843x; 1.1843x over previous
//
#include <hip/hip_runtime.h>
#include <hip/hip_bf16.h>
#include <math.h>

// ---------------------------------------------------------------------------
// ModelFC_49134425866355 on MI355X (gfx950)
//
// out0[row] = dot(LN(gelu(E@W1+b1))*g+b, W2[:,sel]) + b2[sel]
//           = rstd*(D - mu*Gw) + Bw     (algebraic LN+GEMV fusion)
// gemm1p stages A as FP32 via async global_load_lds (no cvt_e pass); fp32->
// bf16 at fragment-read time (2x ds_read_b128 + RNE casts; addrs K-invariant).
// A-tile LDS uses a 16B-granule XOR swizzle pos = g ^ (row&15): read lanes
// hit every bank exactly 2x (2-way aliasing is free on gfx950).
// Stats epilogue via LDS round-trip (r8's shuffle version cost +20 VGPR).
// sel from the exact-fp32 own-row path (rows 520a+j), which runs FIRST.
// 5 kernels: prep_duo | own_lnlog | finalize | gemm1p | out_scores.
// This is the r11 champion configuration (346.5us timed), restored verbatim
// after r13's last-block-merge experiment coincided with a +64us regression
// (profiled gemm1p on identical code swung 149-187us across sessions ->
// large machine variance; champion re-run isolates merge vs noise).
// ---------------------------------------------------------------------------

typedef __bf16 bf16_t;
typedef __bf16  bf16x8  __attribute__((ext_vector_type(8)));
typedef float   floatx4 __attribute__((ext_vector_type(4)));

__device__ __forceinline__ float gelu_exact(float x) {
    return 0.5f * x * (1.0f + erff(x * 0.7071067811865475f));
}
// tanh-form gelu via sigmoid; |err|<~1e-3, below bf16 rounding of bulk path.
__device__ __forceinline__ float gelu_fast(float x) {
    const float z = x * (1.0f + 0.044715f * x * x);
    return __fdividef(x, 1.0f + __expf(-1.5957691216f * z));
}

// async global->LDS, 16B per lane; lds base wave-uniform (HW adds lane*16).
// OFFSET ARG STAYS 0 — nonzero immediate is unverified and broke round 5.
__device__ __forceinline__ void gl_lds16(const void* g, void* l) {
    __builtin_amdgcn_global_load_lds(
        (const __attribute__((address_space(1))) void*)g,
        (__attribute__((address_space(3))) void*)l, 16, 0, 0);
}

// ---------------------------------------------------------------------------
// prep_duo: [0,288) tr_w1 (LDS-tiled transpose) | [288,1056) own_h
// ---------------------------------------------------------------------------
__global__ __launch_bounds__(256) void prep_duo(
        const float* __restrict__ E, const float* __restrict__ W1,
        bf16_t* __restrict__ W1t, float* __restrict__ hpart) {
    __shared__ alignas(16) char smemc[16640];   // max(sT 64x65 fp32, sE 6KB)
    const int bid = blockIdx.x;
    const int tid = threadIdx.x;

    if (bid < 288) {                    // ---- tr_w1: 64x64 LDS-tiled transpose
        float* sT = (float*)smemc;      // [64][65]
        const int bk = bid % 12, bn = bid / 12;
        const int k0 = bk * 64, n0 = bn * 64;
        #pragma unroll
        for (int i = 0; i < 16; ++i) {
            const int idx = tid + i * 256;
            const int kk = idx >> 6, nn = idx & 63;
            sT[kk * 65 + nn] = W1[(size_t)(k0 + kk) * 1536 + n0 + nn];
        }
        __syncthreads();
        #pragma unroll
        for (int i = 0; i < 16; ++i) {
            const int idx = tid + i * 256;
            const int nn = idx >> 6, kk = idx & 63;
            W1t[(size_t)(n0 + nn) * 768 + k0 + kk] = (bf16_t)sT[kk * 65 + nn];
        }
    } else {                            // ---- own_h: hpart[kq][512][1536]
        float* sE = (float*)smemc;      // [8][192]
        const int b  = bid - 288;       // 0..767
        const int a  = b & 63;
        const int rest = b >> 6;        // 0..11
        const int by = rest % 3, kq = rest / 3;

        const float* Ebase = E + (size_t)(520 * a) * 768 + kq * 192;
        for (int idx = tid; idx < 1536; idx += 256) {
            const int row = idx / 192, i = idx - row * 192;
            sE[idx] = Ebase[(size_t)row * 768 + i];
        }
        __syncthreads();

        const int c0 = by * 512 + tid * 2;
        const float* w1p = W1 + (size_t)(kq * 192) * 1536 + c0;
        float ax[8] = {}, ay[8] = {};
        for (int k = 0; k < 192; ++k) {
            const float2 w = *(const float2*)(w1p + (size_t)k * 1536);
            #pragma unroll
            for (int j = 0; j < 8; ++j) {
                const float e = sE[j * 192 + k];   // LDS broadcast
                ax[j] += w.x * e;
                ay[j] += w.y * e;
            }
        }
        #pragma unroll
        for (int j = 0; j < 8; ++j)
            *(float2*)(hpart + (size_t)(kq * 512 + a * 8 + j) * 1536 + c0)
                = make_float2(ax[j], ay[j]);
    }
}

// ---------------------------------------------------------------------------
// own_lnlog: per row (512 blocks): h = gelu_exact(sum of 4 k-partials + b1),
// fp32 LN in LDS, then own[row][100] = LNrow @ W2 + b2 (in-block k-split x2).
// ---------------------------------------------------------------------------
__global__ __launch_bounds__(256) void own_lnlog(
        const float* __restrict__ hpart, const float* __restrict__ b1,
        const float* __restrict__ lng,  const float* __restrict__ lnb,
        const float* __restrict__ W2,   const float* __restrict__ b2,
        float* __restrict__ own) {
    __shared__ float srow[1536];
    __shared__ float red8[8];
    __shared__ float redl[128];
    const int row = blockIdx.x, tid = threadIdx.x;
    const int lane = tid & 63, wv = tid >> 6;

    float x[6];
    #pragma unroll
    for (int i = 0; i < 6; ++i) {
        const int c = tid + i * 256;
        x[i] = gelu_exact(hpart[(size_t)row * 1536 + c]
                        + hpart[(size_t)(512 + row) * 1536 + c]
                        + hpart[(size_t)(1024 + row) * 1536 + c]
                        + hpart[(size_t)(1536 + row) * 1536 + c] + b1[c]);
    }
    float s = 0.f;
    #pragma unroll
    for (int i = 0; i < 6; ++i) s += x[i];
    #pragma unroll
    for (int o = 32; o > 0; o >>= 1) s += __shfl_xor(s, o, 64);
    if (lane == 0) red8[wv] = s;
    __syncthreads();
    const float mu = (red8[0] + red8[1] + red8[2] + red8[3]) * (1.0f / 1536.0f);

    float s2 = 0.f;
    #pragma unroll
    for (int i = 0; i < 6; ++i) { float d = x[i] - mu; s2 += d * d; }
    #pragma unroll
    for (int o = 32; o > 0; o >>= 1) s2 += __shfl_xor(s2, o, 64);
    if (lane == 0) red8[4 + wv] = s2;
    __syncthreads();
    const float rstd = rsqrtf((red8[4] + red8[5] + red8[6] + red8[7]) * (1.0f / 1536.0f) + 1e-12f);

    #pragma unroll
    for (int i = 0; i < 6; ++i) {
        const int c = tid + i * 256;
        srow[c] = (x[i] - mu) * rstd * lng[c] + lnb[c];
    }
    __syncthreads();

    // logits for this row: (d, ks) = (128, 2)
    const int d  = tid & 127;
    const int ks = tid >> 7;
    const int dd = d < 100 ? d : 99;
    float acc = ks ? 0.0f : b2[dd];
    const float* hr = srow + ks * 768;
    for (int k = 0; k < 768; ++k)
        acc += hr[k] * W2[(size_t)(ks * 768 + k) * 100 + dd];
    if (ks) redl[d] = acc;
    __syncthreads();
    if (!ks && d < 100) own[(size_t)row * 100 + d] = acc + redl[d];
}

// ---------------------------------------------------------------------------
// finalize: VG_scores / VG_index (fp32-exact, first-max), then sel-dependent
// constants: u = g.*W2[:,sel], Gw = sum(u), Bw = sum(b.*W2[:,sel]) + b2[sel].
// ONE block, 512 threads.
// ---------------------------------------------------------------------------
__global__ __launch_bounds__(512) void finalize(
        const float* __restrict__ own, const float* __restrict__ W2,
        const float* __restrict__ b2,  const float* __restrict__ lng,
        const float* __restrict__ lnb, float* __restrict__ out,
        float* __restrict__ u, float* __restrict__ gwbw) {
    __shared__ int ssel;
    __shared__ float rg[8], rb[8];
    const int e = threadIdx.x;                    // 0..511
    const int lane = e & 63, wv = e >> 6;
    const float* r = own + (size_t)e * 100;
    float best = r[0]; int bi = 0;
    for (int i = 1; i < 100; ++i) {
        const float v = r[i];
        if (v > best) { best = v; bi = i; }       // strict > keeps first max
    }
    float s = 0.f;
    for (int i = 0; i < 100; ++i) s += expf(r[i] - best);
    out[262144 + e] = 1.0f / s;                   // VG_scores
    out[262656 + e] = (float)bi;                  // VG_scores_index
    if (e == 511) ssel = bi;
    __syncthreads();
    const int sel = ssel;

    float gw = 0.f, bw = 0.f;
    #pragma unroll
    for (int c = e; c < 1536; c += 512) {
        const float wv2 = W2[(size_t)c * 100 + sel];
        const float uu = lng[c] * wv2;
        u[c] = uu;
        gw += uu;
        bw += lnb[c] * wv2;
    }
    #pragma unroll
    for (int o = 32; o > 0; o >>= 1) {
        gw += __shfl_xor(gw, o, 64);
        bw += __shfl_xor(bw, o, 64);
    }
    if (lane == 0) { rg[wv] = gw; rb[wv] = bw; }
    __syncthreads();
    if (e == 0) {
        float G = 0.f, B = 0.f;
        #pragma unroll
        for (int i = 0; i < 8; ++i) { G += rg[i]; B += rb[i]; }
        gwbw[0] = G;
        gwbw[1] = B + b2[sel];
    }
}

// ---------------------------------------------------------------------------
// gemm1p: [32768,768]x[768,1536], 128x128 tile, BK=64, 12 K-tiles.
// A staged as FP32 via global_load_lds into a granule-swizzled LDS tile
// (pos = g ^ (row&15), 16B granules, 16/row); fragments read as 2x b128 +
// RNE cast to bf16 (bit-identical numerics to the old cvt_e path).
// B staged via global_load_lds (bf16, source-swizzled, unchanged).
// Epilogue: LDS round-trip stats (S1,S2,D). No act matrix.
// ---------------------------------------------------------------------------
__global__ __launch_bounds__(256) void gemm1p(
        const float* __restrict__ E, const bf16_t* __restrict__ Bt,
        const float* __restrict__ bias, const float* __restrict__ u,
        float* __restrict__ pS1, float* __restrict__ pS2,
        float* __restrict__ pD) {
    constexpr int K = 768;
    __shared__ alignas(16) char smem[49152];   // sAf 32KB | sB 16KB; epi reuse
    float*  sAf = (float*)smem;                // [128][64] fp32, swizzled
    bf16_t* sB  = (bf16_t*)(smem + 32768);     // [128][64] bf16, swizzled

    // XCD-aware remap: 12 n-tiles of one m-tile land on one XCD
    const int linear = blockIdx.x + gridDim.x * blockIdx.y;
    const int xcd  = linear & 7;
    const int slot = linear >> 3;
    const int bx = slot % gridDim.x;
    const int by = (slot / gridDim.x) * 8 + xcd;

    const int tid  = threadIdx.x;
    const int lane = tid & 63;
    const int wave = tid >> 6;
    const int wr = wave >> 1, wc = wave & 1;
    const int m0 = by * 128;
    const int n0 = bx * 128;
    const int q  = lane >> 4;
    const int l15 = lane & 15;

    // ---- A staging bases: slot s = c*256+tid; r = s>>4 (16 granules/row),
    //      pos = s&15, logical granule g = pos ^ (r&15); source = row r, g*4.
    const float* gAf[8]; float* lAf[8];
    #pragma unroll
    for (int c = 0; c < 8; ++c) {
        const int s   = c * 256 + tid;
        const int r   = s >> 4;
        const int pos = s & 15;
        const int g   = pos ^ (r & 15);
        gAf[c] = E + (size_t)(m0 + r) * K + g * 4;
        lAf[c] = sAf + (c * 256 + wave * 64) * 4;   // wave-uniform base
    }
    // ---- B staging bases (bf16, 8 granules of 16B per row, col^row&7)
    const bf16_t* gB[4]; bf16_t* lB[4];
    #pragma unroll
    for (int c = 0; c < 4; ++c) {
        const int s    = c * 256 + tid;
        const int row  = s >> 3;
        const int col  = s & 7;
        const int gcol = col ^ (row & 7);
        gB[c] = Bt + (size_t)(n0 + row) * K + gcol * 8;
        lB[c] = sB + (c * 256 + wave * 64) * 8;
    }
    // ---- read bases (K-step invariant)
    const float* rAf[4]; const bf16_t* rB[4];
    #pragma unroll
    for (int t4 = 0; t4 < 4; ++t4) {
        rAf[t4] = sAf + (wr * 64 + t4 * 16 + l15) * 64;  // row&15 == l15
        rB[t4]  = sB + (wc * 64 + t4 * 16 + l15) * 64;
    }
    const int q2 = q * 2;
    // A fragment: logical chunk j = ks*4+q -> granules 2j, 2j+1 at swizzled
    // positions (2j+h)^l15; float offsets = pos*4.
    const int oA00 = ((q2)     ^ l15) * 4, oA01 = ((q2 + 1) ^ l15) * 4;
    const int oA10 = ((q2 + 8) ^ l15) * 4, oA11 = ((q2 + 9) ^ l15) * 4;
    const int c0 = ((q)     ^ (lane & 7)) * 8;   // B: rB row & 7 == lane & 7
    const int c1 = ((4 + q) ^ (lane & 7)) * 8;

    floatx4 acc[4][4] = {};

    #pragma unroll
    for (int kt = 0; kt < 12; ++kt) {
        const int k0 = kt * 64;
        __syncthreads();   // prev compute done before LDS overwrite
        #pragma unroll
        for (int c = 0; c < 4; ++c) gl_lds16(gB[c] + k0, lB[c]);
        #pragma unroll
        for (int c = 0; c < 8; ++c) gl_lds16(gAf[c] + k0, lAf[c]);
        __syncthreads();   // drain DMA, then barrier

        #pragma unroll
        for (int ks = 0; ks < 2; ++ks) {
            const int co  = ks ? c1 : c0;
            const int oa0 = ks ? oA10 : oA00;
            const int oa1 = ks ? oA11 : oA01;
            bf16x8 af[4], bfr[4];
            #pragma unroll
            for (int t4 = 0; t4 < 4; ++t4) {
                const float4 v0 = *(const float4*)(rAf[t4] + oa0);
                const float4 v1 = *(const float4*)(rAf[t4] + oa1);
                af[t4][0] = (bf16_t)v0.x; af[t4][1] = (bf16_t)v0.y;
                af[t4][2] = (bf16_t)v0.z; af[t4][3] = (bf16_t)v0.w;
                af[t4][4] = (bf16_t)v1.x; af[t4][5] = (bf16_t)v1.y;
                af[t4][6] = (bf16_t)v1.z; af[t4][7] = (bf16_t)v1.w;
                bfr[t4] = *(const bf16x8*)(rB[t4] + co);
            }
            #pragma unroll
            for (int mt = 0; mt < 4; ++mt)
                #pragma unroll
                for (int nt = 0; nt < 4; ++nt)
                    acc[mt][nt] = __builtin_amdgcn_mfma_f32_16x16x32_bf16(
                        af[mt], bfr[nt], acc[mt][nt], 0, 0, 0);
        }
    }

    // ---- stats epilogue via LDS (low VGPR). C/D layout: col=l15, row=q*4+r.
    __syncthreads();                       // all tile ds_reads done
    bf16_t* sh = (bf16_t*)smem;            // [128][130] bf16 = 33280 B
    float*  su = (float*)(smem + 33280);   // u[n0..n0+127]          512 B
    float*  sp = (float*)(smem + 33792);   // [256][3] partials     3072 B

    if (tid < 128) su[tid] = u[n0 + tid];
    float bias4[4];
    #pragma unroll
    for (int nt = 0; nt < 4; ++nt) bias4[nt] = bias[n0 + wc * 64 + nt * 16 + l15];

    #pragma unroll
    for (int mt = 0; mt < 4; ++mt)
        #pragma unroll
        for (int nt = 0; nt < 4; ++nt)
            #pragma unroll
            for (int r = 0; r < 4; ++r) {
                const int rowl = wr * 64 + mt * 16 + q * 4 + r;
                const int coll = wc * 64 + nt * 16 + l15;
                sh[rowl * 130 + coll] = (bf16_t)gelu_fast(acc[mt][nt][r] + bias4[nt]);
            }
    __syncthreads();

    // phase 2: thread = (row, half); reduce 64 cols each
    {
        const int rowl = tid >> 1, half = tid & 1;
        const bf16_t* hp = sh + rowl * 130 + half * 64;
        const float*  up = su + half * 64;
        float s1 = 0.f, s2 = 0.f, dd = 0.f;
        #pragma unroll
        for (int c = 0; c < 64; ++c) {
            const float v = (float)hp[c];
            s1 += v; s2 += v * v; dd += v * up[c];
        }
        sp[tid * 3 + 0] = s1; sp[tid * 3 + 1] = s2; sp[tid * 3 + 2] = dd;
    }
    __syncthreads();
    if (tid < 128) {
        const float* p0 = sp + (2 * tid) * 3;
        const float* p1 = sp + (2 * tid + 1) * 3;
        const size_t idx = (size_t)bx * 32768 + (m0 + tid);
        pS1[idx] = p0[0] + p1[0];
        pS2[idx] = p0[1] + p1[1];
        pD[idx]  = p0[2] + p1[2];
    }
}

// ---------------------------------------------------------------------------
// out_scores: out[t*8+k] = rstd*(D - mu*Gw) + Bw   (32768 threads)
// ---------------------------------------------------------------------------
__global__ __launch_bounds__(256) void out_scores(
        const float* __restrict__ pS1, const float* __restrict__ pS2,
        const float* __restrict__ pD,  const float* __restrict__ gwbw,
        float* __restrict__ out) {
    const int t = blockIdx.x * 256 + threadIdx.x;   // 32768 exactly
    float s1 = 0.f, s2 = 0.f, d = 0.f;
    #pragma unroll
    for (int nt = 0; nt < 12; ++nt) {
        const size_t idx = (size_t)nt * 32768 + t;
        s1 += pS1[idx]; s2 += pS2[idx]; d += pD[idx];
    }
    const float mu   = s1 * (1.0f / 1536.0f);
    const float var  = s2 * (1.0f / 1536.0f) - mu * mu;
    const float rstd = rsqrtf(var + 1e-12f);
    const float v = rstd * (d - mu * gwbw[0]) + gwbw[1];
    const float4 f = make_float4(v, v, v, v);
    float4* o = (float4*)(out + (size_t)t * 8);
    o[0] = f; o[1] = f;
}

// ---------------------------------------------------------------------------
extern "C" void kernel_launch(void* const* d_in, const int* in_sizes, int n_in,
                              void* d_out, int out_size, void* d_ws, size_t ws_size,
                              hipStream_t stream) {
    const float* E   = (const float*)d_in[0];
    const float* W1  = (const float*)d_in[1];
    const float* b1  = (const float*)d_in[2];
    const float* lng = (const float*)d_in[3];
    const float* lnb = (const float*)d_in[4];
    const float* W2  = (const float*)d_in[5];
    const float* b2  = (const float*)d_in[6];
    float* out = (float*)d_out;

    char* w = (char*)d_ws;
    auto carve = [&](size_t bytes) {
        void* p = (void*)w;
        w += (bytes + 255) & ~(size_t)255;
        return p;
    };
    bf16_t* W1t   = (bf16_t*)carve((size_t)1536 * 768 * 2);    //  2.4 MB
    float*  hpart = (float*)carve((size_t)4 * 512 * 1536 * 4); // 12.6 MB
    float*  own   = (float*)carve((size_t)512 * 100 * 4);
    float*  u     = (float*)carve(1536 * 4);
    float*  gwbw  = (float*)carve(256);
    float*  pS1   = (float*)carve((size_t)12 * 32768 * 4);     //  1.6 MB
    float*  pS2   = (float*)carve((size_t)12 * 32768 * 4);
    float*  pD    = (float*)carve((size_t)12 * 32768 * 4);

    // 1) prep: W1 transpose (tiled) + own-row k-partials (no cvt_e pass)
    prep_duo<<<1056, 256, 0, stream>>>(E, W1, W1t, hpart);
    // 2) own rows: sum partials + gelu + LN + logits
    own_lnlog<<<512, 256, 0, stream>>>(hpart, b1, lng, lnb, W2, b2, own);
    // 3) argmax/softmax -> VG outputs + sel-derived constants u/Gw/Bw
    finalize<<<1, 512, 0, stream>>>(own, W2, b2, lng, lnb, out, u, gwbw);
    // 4) fused GEMM (A = fp32 E via async DMA, cvt at fragment read)
    gemm1p<<<dim3(12, 256), 256, 0, stream>>>(E, W1t, b1, u, pS1, pS2, pD);
    // 5) combine partials -> output 0
    out_scores<<<128, 256, 0, stream>>>(pS1, pS2, pD, gwbw, out);
}